// Round 5
// baseline (314.666 us; speedup 1.0000x reference)
//
#include <hip/hip_runtime.h>
#include <hip/hip_bf16.h>
#include <hip/hip_fp16.h>
#include <math.h>

// Problem constants
#define BSZ 8
#define LSEQ 4096
#define HDIM 512
#define PDIM 256
#define MROWS (BSZ * LSEQ)        // 32768
#define NDIM 512                  // 2*PDIM
#define CHUNK 32
#define NCHUNK (LSEQ / CHUNK)     // 128
#define LOG2CHUNK 5

typedef __attribute__((ext_vector_type(8))) short bf16x8;
typedef __attribute__((ext_vector_type(4))) float f32x4;

// ---------------------------------------------------------------------------
// Per-p parameter kernel (256 threads, 1 block). Double-precision
// transcendentals ONCE per p. Emits f (B_bar factor), a=Lambda_bar,
// al=Lambda_bar^CHUNK.
// ---------------------------------------------------------------------------
__global__ void precompute_params(const float* __restrict__ Lre,
                                  const float* __restrict__ Lim,
                                  const float* __restrict__ logstep,
                                  float* __restrict__ f_re, float* __restrict__ f_im,
                                  float* __restrict__ a_re, float* __restrict__ a_im,
                                  float* __restrict__ al_re, float* __restrict__ al_im) {
    int p = threadIdx.x;
    if (p >= PDIM) return;
    double step = exp((double)logstep[p]);
    double dlr = (double)Lre[p], dli = (double)Lim[p];
    double mag = exp(dlr * step);
    double ar = mag * cos(dli * step);
    double ai = mag * sin(dli * step);
    double den = dlr * dlr + dli * dli;
    double nr = ar - 1.0, ni = ai;
    f_re[p] = (float)((nr * dlr + ni * dli) / den);
    f_im[p] = (float)((ni * dlr - nr * dli) / den);
    a_re[p] = (float)ar;
    a_im[p] = (float)ai;
    double cr = ar, ci = ai;
#pragma unroll
    for (int i = 0; i < LOG2CHUNK; ++i) {  // ^CHUNK
        double tr = cr * cr - ci * ci;
        double ti = 2.0 * cr * ci;
        cr = tr; ci = ti;
    }
    al_re[p] = (float)cr;
    al_im[p] = (float)ci;
}

// ---------------------------------------------------------------------------
// Merged prep kernel: convert_x (blocks [0, NCONV)), W1T (next 512 blocks),
// W2T (next 512).  Uniform branch per block.
// ---------------------------------------------------------------------------
#define NCONV (MROWS * HDIM / 4 / 256)   // 16384
__global__ __launch_bounds__(256) void prep(
    const float* __restrict__ x, __hip_bfloat16* __restrict__ xb,
    const float* __restrict__ f_re, const float* __restrict__ f_im,
    const float* __restrict__ Bmat, __hip_bfloat16* __restrict__ W1T,
    const float* __restrict__ Cmat, __hip_bfloat16* __restrict__ W2T) {
    const int bid = blockIdx.x;
    const int tid = threadIdx.x;
    if (bid < NCONV) {
        int i = bid * 256 + tid;
        float4 v = ((const float4*)x)[i];
        union { ushort4 u; __hip_bfloat16 h[4]; } o;
        o.h[0] = __float2bfloat16(v.x);
        o.h[1] = __float2bfloat16(v.y);
        o.h[2] = __float2bfloat16(v.z);
        o.h[3] = __float2bfloat16(v.w);
        ((ushort4*)xb)[i] = o.u;
    } else if (bid < NCONV + 512) {
        int idx = (bid - NCONV) * 256 + tid;   // p*H + h
        int p = idx / HDIM, h = idx % HDIM;
        float fr = f_re[p], fi = f_im[p];
        float br = Bmat[(size_t)(p * HDIM + h) * 2 + 0];
        float bi = Bmat[(size_t)(p * HDIM + h) * 2 + 1];
        W1T[(size_t)(2 * p) * HDIM + h]     = __float2bfloat16(fr * br - fi * bi);
        W1T[(size_t)(2 * p + 1) * HDIM + h] = __float2bfloat16(fr * bi + fi * br);
    } else {
        int idx = (bid - NCONV - 512) * 256 + tid;  // h*P + p
        int h = idx / PDIM, p = idx % PDIM;
        float cr = Cmat[(size_t)(h * PDIM + p) * 2 + 0];
        float ci = Cmat[(size_t)(h * PDIM + p) * 2 + 1];
        W2T[(size_t)h * NDIM + 2 * p]     = __float2bfloat16(2.0f * cr);
        W2T[(size_t)h * NDIM + 2 * p + 1] = __float2bfloat16(-2.0f * ci);
    }
}

// ---------------------------------------------------------------------------
// BARRIER-FREE STREAMING GEMM: C(MxN, OT) = A(MxK) @ BT(NxK)^T [+ D*xskip]
// Exploits tiny weights (N=K=512): each block stages a 64-col W-slice
// (64 x 512 bf16, row-padded to 1040 B -> 2-way LDS banks = free) into LDS
// ONCE, one __syncthreads, then ZERO barriers: each wave independently
// streams 64-row A-chunks with A-frags loaded global->VGPR (3-deep k-frag
// register pipeline), W-frags from LDS, 256 MFMA/chunk.
// Waves never lockstep -> no barrier-drain stalls (R1/R2/R4 all pinned at
// ~44 us under barriered K-loops of every flavor).
// Grid: 512 blocks = 8 col-groups x 64 stripes, id = g*64+s so a stripe's
// 8 col-group blocks (ids == s mod 8) share one XCD's L2 (A set = 4 MB/XCD).
// All blocks co-resident: LDS 65 KB -> 2 blocks/CU, VGPR capped via
// __launch_bounds__(256,2).
// ---------------------------------------------------------------------------
#define WROWB 1040   // padded LDS row bytes (520 bf16): 260 dwords % 32 = 4

template <typename OT, bool SKIP>
__global__ __launch_bounds__(256, 2) void gemm_stream(
    const __hip_bfloat16* __restrict__ A,   // M x K
    const __hip_bfloat16* __restrict__ BT,  // N x K
    OT* __restrict__ C,                     // M x N
    const float* __restrict__ Dvec,
    const __hip_bfloat16* __restrict__ Xskip,
    int M, int N, int K) {
    __shared__ char smW[64 * WROWB];        // 66560 B

    const int tid = threadIdx.x;
    const int lane = tid & 63;
    const int wave = tid >> 6;             // 0..3
    const int g = blockIdx.x >> 6;         // col group 0..7
    const int s = blockIdx.x & 63;         // stripe 0..63
    const int col0 = g * 64;
    const int quad = lane >> 4;            // 0..3
    const int l15 = lane & 15;

    // ---- Stage W slice once: row r holds BT[col0+r][0..511] (1 KB) ----
    for (int rr = 0; rr < 16; ++rr) {
        const int r = wave * 16 + rr;
        const __hip_bfloat16* gW = BT + (size_t)(col0 + r) * K + lane * 8;
        __builtin_amdgcn_global_load_lds(
            (const __attribute__((address_space(1))) void*)gW,
            (__attribute__((address_space(3))) void*)(smW + r * WROWB),
            16, 0, 0);
    }
    __syncthreads();   // ONLY barrier in the kernel

    // W-frag read: lane -> row j*16+l15, k = kf*32 + quad*8 (16 B)
    auto ldw = [&](int j, int kf) -> bf16x8 {
        return *(const bf16x8*)(smW + (j * 16 + l15) * WROWB + kf * 64 + quad * 16);
    };

    const int nkf = K >> 5;                // 16
#pragma unroll 1
    for (int cc = 0; cc < 2; ++cc) {
        const int mrow0 = (s * 8 + wave + cc * 4) * 64;

        f32x4 acc[4][4] = {};
        bf16x8 a[3][4];
        // A-frag: lane -> row mrow0+i*16+l15, k = kf*32 + quad*8 (16 B; the
        // 4 quads of a 16-lane row-group cover one full 64 B line per row)
        auto lda = [&](int kf, int buf) {
#pragma unroll
            for (int i = 0; i < 4; ++i) {
                const __hip_bfloat16* gA =
                    A + (size_t)(mrow0 + i * 16 + l15) * K + kf * 32 + quad * 8;
                a[buf][i] = *(const bf16x8*)gA;
            }
        };

        lda(0, 0);
        lda(1, 1);
#pragma unroll
        for (int kf = 0; kf < 16; ++kf) {
            const int buf = kf % 3;
            if (kf + 2 < 16) lda(kf + 2, (kf + 2) % 3);
            bf16x8 w0 = ldw(0, kf), w1 = ldw(1, kf),
                   w2 = ldw(2, kf), w3 = ldw(3, kf);
#pragma unroll
            for (int i = 0; i < 4; ++i) {
                acc[i][0] = __builtin_amdgcn_mfma_f32_16x16x32_bf16(a[buf][i], w0, acc[i][0], 0, 0, 0);
                acc[i][1] = __builtin_amdgcn_mfma_f32_16x16x32_bf16(a[buf][i], w1, acc[i][1], 0, 0, 0);
                acc[i][2] = __builtin_amdgcn_mfma_f32_16x16x32_bf16(a[buf][i], w2, acc[i][2], 0, 0, 0);
                acc[i][3] = __builtin_amdgcn_mfma_f32_16x16x32_bf16(a[buf][i], w3, acc[i][3], 0, 0, 0);
            }
        }

        // Epilogue: D row = quad*4 + r, col = l15 (m89/m91-verified layout)
#pragma unroll
        for (int i = 0; i < 4; ++i) {
            const int mbase = mrow0 + i * 16 + quad * 4;
#pragma unroll
            for (int j = 0; j < 4; ++j) {
                const int col = col0 + j * 16 + l15;
                const float dv = SKIP ? Dvec[col] : 0.0f;
#pragma unroll
                for (int r = 0; r < 4; ++r) {
                    const size_t m = (size_t)(mbase + r);
                    float v = acc[i][j][r];
                    if (SKIP) v += dv * __bfloat162float(Xskip[m * N + col]);
                    if constexpr (sizeof(OT) == 2) {
                        C[m * N + col] = OT(v);
                    } else {
                        C[m * N + col] = v;
                    }
                }
            }
        }
    }
}

// ---------------------------------------------------------------------------
// Scan pass A: per (b, chunk), per-p thread: local scan from zero over CHUNK
// steps; write chunk-end state.  CHUNK=32 -> 1024 blocks (4/CU).
// ---------------------------------------------------------------------------
__global__ __launch_bounds__(256) void scan_chunks(const __half2* __restrict__ Bu2,
                                                   const float* __restrict__ a_re,
                                                   const float* __restrict__ a_im,
                                                   float2* __restrict__ S) {
    int b = blockIdx.x / NCHUNK;
    int c = blockIdx.x % NCHUNK;
    int p = threadIdx.x;
    float ar = a_re[p], ai = a_im[p];
    float sr = 0.0f, si = 0.0f;
    size_t m0 = (size_t)b * LSEQ + (size_t)c * CHUNK;
    for (int j = 0; j < CHUNK; ++j) {
        float2 u = __half22float2(Bu2[(m0 + j) * PDIM + p]);
        float nsr = ar * sr - ai * si + u.x;
        float nsi = ar * si + ai * sr + u.y;
        sr = nsr; si = nsi;
    }
    S[(size_t)(b * NCHUNK + c) * PDIM + p] = make_float2(sr, si);
}

// ---------------------------------------------------------------------------
// Scan pass B: wave-parallel chunk-carry scan over NCHUNK=128 chunks.
// One wave per (b,p); lane handles chunks 2*lane, 2*lane+1.
// ---------------------------------------------------------------------------
__global__ __launch_bounds__(256) void scan_carry(const float2* __restrict__ S,
                                                  const float* __restrict__ al_re,
                                                  const float* __restrict__ al_im,
                                                  float2* __restrict__ carry) {
    const int wid = blockIdx.x * 4 + (threadIdx.x >> 6);  // 0..2047
    const int b = wid >> 8;        // 0..7
    const int p = wid & 255;       // 0..255
    const int lane = threadIdx.x & 63;
    const int c0 = 2 * lane, c1 = 2 * lane + 1;
    float alr = al_re[p], ali = al_im[p];
    float2 s0 = S[(size_t)(b * NCHUNK + c0) * PDIM + p];
    float2 s1 = S[(size_t)(b * NCHUNK + c1) * PDIM + p];
    // pair combine (earlier=c0, later=c1): A = al^2, b = al*s0 + s1
    float Ar = alr * alr - ali * ali;
    float Ai = 2.0f * alr * ali;
    float br = alr * s0.x - ali * s0.y + s1.x;
    float bi = alr * s0.y + ali * s0.x + s1.y;
#pragma unroll
    for (int d = 1; d < 64; d <<= 1) {
        float pAr = __shfl_up(Ar, d);
        float pAi = __shfl_up(Ai, d);
        float pbr = __shfl_up(br, d);
        float pbi = __shfl_up(bi, d);
        if (lane >= d) {
            float nAr = Ar * pAr - Ai * pAi;
            float nAi = Ar * pAi + Ai * pAr;
            float nbr = Ar * pbr - Ai * pbi + br;
            float nbi = Ar * pbi + Ai * pbr + bi;
            Ar = nAr; Ai = nAi; br = nbr; bi = nbi;
        }
    }
    // exclusive state through pair lane-1 = carry for chunk c0
    float er = __shfl_up(br, 1);
    float ei = __shfl_up(bi, 1);
    if (lane == 0) { er = 0.0f; ei = 0.0f; }
    carry[(size_t)(b * NCHUNK + c0) * PDIM + p] = make_float2(er, ei);
    // carry for c1 = al*carry(c0) + s0
    carry[(size_t)(b * NCHUNK + c1) * PDIM + p] =
        make_float2(alr * er - ali * ei + s0.x, alr * ei + ali * er + s0.y);
}

// Scan pass C: local scan seeded with carry; write xs as bf16 (interleaved).
__global__ __launch_bounds__(256) void scan_apply(const __half2* __restrict__ Bu2,
                                                  const float* __restrict__ a_re,
                                                  const float* __restrict__ a_im,
                                                  const float2* __restrict__ carry,
                                                  ushort2* __restrict__ xsb2) {
    int b = blockIdx.x / NCHUNK;
    int c = blockIdx.x % NCHUNK;
    int p = threadIdx.x;
    float ar = a_re[p], ai = a_im[p];
    float2 c0 = carry[(size_t)(b * NCHUNK + c) * PDIM + p];
    float sr = c0.x, si = c0.y;
    size_t m0 = (size_t)b * LSEQ + (size_t)c * CHUNK;
    for (int j = 0; j < CHUNK; ++j) {
        size_t idx = (m0 + j) * PDIM + p;
        float2 u = __half22float2(Bu2[idx]);
        float nsr = ar * sr - ai * si + u.x;
        float nsi = ar * si + ai * sr + u.y;
        sr = nsr; si = nsi;
        union { ushort2 u2; __hip_bfloat16 h[2]; } o;
        o.h[0] = __float2bfloat16(sr);
        o.h[1] = __float2bfloat16(si);
        xsb2[idx] = o.u2;
    }
}

// ---------------------------------------------------------------------------
extern "C" void kernel_launch(void* const* d_in, const int* in_sizes, int n_in,
                              void* d_out, int out_size, void* d_ws, size_t ws_size,
                              hipStream_t stream) {
    const float* x       = (const float*)d_in[0];
    const float* Lre     = (const float*)d_in[1];
    const float* Lim     = (const float*)d_in[2];
    const float* Bmat    = (const float*)d_in[3];
    const float* Cmat    = (const float*)d_in[4];
    const float* Dvec    = (const float*)d_in[5];
    const float* logstep = (const float*)d_in[6];
    float* out = (float*)d_out;

    char* ws = (char*)d_ws;
    const size_t MB = 1u << 20;
    __hip_bfloat16* xb  = (__hip_bfloat16*)(ws + 0);         // 32 MB
    __hip_bfloat16* xsb = (__hip_bfloat16*)(ws + 32 * MB);   // 32 MB
    __half* Bu          = (__half*)(ws + 64 * MB);           // 32 MB
    __hip_bfloat16* W1T = (__hip_bfloat16*)(ws + 96 * MB);   // 0.5 MB
    __hip_bfloat16* W2T = (__hip_bfloat16*)(ws + 96 * MB + 512 * 1024);
    float*  a_re  = (float*)(ws + 97 * MB);
    float*  a_im  = (float*)(ws + 97 * MB + 4096);
    float*  f_re  = (float*)(ws + 97 * MB + 8192);
    float*  f_im  = (float*)(ws + 97 * MB + 12288);
    float*  al_re = (float*)(ws + 97 * MB + 16384);
    float*  al_im = (float*)(ws + 97 * MB + 20480);
    float2* S     = (float2*)(ws + 98 * MB);                 // 2 MB
    float2* carry = (float2*)(ws + 100 * MB);                // 2 MB

    // 1. Params (1 block), then merged prep (convert + W1 + W2)
    precompute_params<<<1, 256, 0, stream>>>(Lre, Lim, logstep,
                                             f_re, f_im, a_re, a_im, al_re, al_im);
    prep<<<NCONV + 1024, 256, 0, stream>>>(x, xb, f_re, f_im, Bmat, W1T, Cmat, W2T);

    // 2. GEMM1: Bu(fp16) = xb @ W1T^T  (512 blocks = 8 col-groups x 64 stripes)
    gemm_stream<__half, false><<<512, 256, 0, stream>>>(
        xb, W1T, Bu, nullptr, nullptr, MROWS, NDIM, HDIM);

    // 3. Scan (3-pass chunked), emits xs as bf16
    scan_chunks<<<BSZ * NCHUNK, 256, 0, stream>>>((const __half2*)Bu, a_re, a_im, S);
    scan_carry<<<BSZ * PDIM / 4, 256, 0, stream>>>(S, al_re, al_im, carry);
    scan_apply<<<BSZ * NCHUNK, 256, 0, stream>>>((const __half2*)Bu, a_re, a_im,
                                                 carry, (ushort2*)xsb);

    // 4. GEMM2: out = xsb @ W2T^T + D*xb
    gemm_stream<float, true><<<512, 256, 0, stream>>>(
        xsb, W2T, out, Dvec, xb, MROWS, HDIM, NDIM);
}

// Round 7
// 242.234 us; speedup vs baseline: 1.2990x; 1.2990x over previous
//
#include <hip/hip_runtime.h>
#include <hip/hip_bf16.h>
#include <hip/hip_fp16.h>
#include <math.h>

// Problem constants
#define BSZ 8
#define LSEQ 4096
#define HDIM 512
#define PDIM 256
#define MROWS (BSZ * LSEQ)        // 32768
#define NDIM 512                  // 2*PDIM
#define CHUNK 32
#define NCHUNK (LSEQ / CHUNK)     // 128
#define LOG2CHUNK 5

typedef __attribute__((ext_vector_type(8))) short bf16x8;
typedef __attribute__((ext_vector_type(4))) float f32x4;

// ---------------------------------------------------------------------------
// Per-p parameter kernel (256 threads, 1 block). Double-precision
// transcendentals ONCE per p. Emits f (B_bar factor), a=Lambda_bar,
// al=Lambda_bar^CHUNK.
// ---------------------------------------------------------------------------
__global__ void precompute_params(const float* __restrict__ Lre,
                                  const float* __restrict__ Lim,
                                  const float* __restrict__ logstep,
                                  float* __restrict__ f_re, float* __restrict__ f_im,
                                  float* __restrict__ a_re, float* __restrict__ a_im,
                                  float* __restrict__ al_re, float* __restrict__ al_im) {
    int p = threadIdx.x;
    if (p >= PDIM) return;
    double step = exp((double)logstep[p]);
    double dlr = (double)Lre[p], dli = (double)Lim[p];
    double mag = exp(dlr * step);
    double ar = mag * cos(dli * step);
    double ai = mag * sin(dli * step);
    double den = dlr * dlr + dli * dli;
    double nr = ar - 1.0, ni = ai;
    f_re[p] = (float)((nr * dlr + ni * dli) / den);
    f_im[p] = (float)((ni * dlr - nr * dli) / den);
    a_re[p] = (float)ar;
    a_im[p] = (float)ai;
    double cr = ar, ci = ai;
#pragma unroll
    for (int i = 0; i < LOG2CHUNK; ++i) {  // ^CHUNK
        double tr = cr * cr - ci * ci;
        double ti = 2.0 * cr * ci;
        cr = tr; ci = ti;
    }
    al_re[p] = (float)cr;
    al_im[p] = (float)ci;
}

// ---------------------------------------------------------------------------
// Merged prep kernel: convert_x (blocks [0, NCONV)), W1T (next 512 blocks),
// W2T (next 512).  Uniform branch per block.
// ---------------------------------------------------------------------------
#define NCONV (MROWS * HDIM / 4 / 256)   // 16384
__global__ __launch_bounds__(256) void prep(
    const float* __restrict__ x, __hip_bfloat16* __restrict__ xb,
    const float* __restrict__ f_re, const float* __restrict__ f_im,
    const float* __restrict__ Bmat, __hip_bfloat16* __restrict__ W1T,
    const float* __restrict__ Cmat, __hip_bfloat16* __restrict__ W2T) {
    const int bid = blockIdx.x;
    const int tid = threadIdx.x;
    if (bid < NCONV) {
        int i = bid * 256 + tid;
        float4 v = ((const float4*)x)[i];
        union { ushort4 u; __hip_bfloat16 h[4]; } o;
        o.h[0] = __float2bfloat16(v.x);
        o.h[1] = __float2bfloat16(v.y);
        o.h[2] = __float2bfloat16(v.z);
        o.h[3] = __float2bfloat16(v.w);
        ((ushort4*)xb)[i] = o.u;
    } else if (bid < NCONV + 512) {
        int idx = (bid - NCONV) * 256 + tid;   // p*H + h
        int p = idx / HDIM, h = idx % HDIM;
        float fr = f_re[p], fi = f_im[p];
        float br = Bmat[(size_t)(p * HDIM + h) * 2 + 0];
        float bi = Bmat[(size_t)(p * HDIM + h) * 2 + 1];
        W1T[(size_t)(2 * p) * HDIM + h]     = __float2bfloat16(fr * br - fi * bi);
        W1T[(size_t)(2 * p + 1) * HDIM + h] = __float2bfloat16(fr * bi + fi * br);
    } else {
        int idx = (bid - NCONV - 512) * 256 + tid;  // h*P + p
        int h = idx / PDIM, p = idx % PDIM;
        float cr = Cmat[(size_t)(h * PDIM + p) * 2 + 0];
        float ci = Cmat[(size_t)(h * PDIM + p) * 2 + 1];
        W2T[(size_t)h * NDIM + 2 * p]     = __float2bfloat16(2.0f * cr);
        W2T[(size_t)h * NDIM + 2 * p + 1] = __float2bfloat16(-2.0f * ci);
    }
}

// ---------------------------------------------------------------------------
// bf16 MFMA GEMM (R4-proven, 44 us, verbatim): C = A @ BT^T [+ D*xskip]
// 128x128 tile, BK=32, 4 waves (2x2), 3-buffer counted-vmcnt pipeline,
// T2 both-sides XOR swizzle, row-fast grid for XCD L2 sharing.
// ---------------------------------------------------------------------------
template <typename OT, bool SKIP>
__global__ __launch_bounds__(256) void gemm_bt(
    const __hip_bfloat16* __restrict__ A,   // M x K
    const __hip_bfloat16* __restrict__ BT,  // N x K
    OT* __restrict__ C,                     // M x N
    const float* __restrict__ Dvec,
    const __hip_bfloat16* __restrict__ Xskip,
    int M, int N, int K) {
    __shared__ __hip_bfloat16 smA[3 * 128 * 32];   // 24 KB
    __shared__ __hip_bfloat16 smB[3 * 128 * 32];   // 24 KB

    const int tid = threadIdx.x;
    const int lane = tid & 63;
    const int wave = tid >> 6;            // 0..3
    const int row0 = blockIdx.x * 128;    // row tile fast dim
    const int col0 = blockIdx.y * 128;
    const int wm = (wave >> 1) * 64;
    const int wn = (wave & 1) * 64;

    const int sr = lane >> 2;             // staged row within 16-row chunk
    const int swz_st = ((lane >> 2) & 3) ^ ((lane >> 4) & 3);   // sw of staged row
    const int sk = (((lane & 3) ^ swz_st) * 8);                 // swizzled k-seg (elems)
    const int quad = lane >> 4;           // 0..3
    const int l15 = lane & 15;
    const int rq = ((quad ^ ((l15 & 3) ^ ((l15 >> 2) & 3))) * 8);  // swizzled read seg

    f32x4 acc[4][4] = {};

    auto stage = [&](int buf, int t) {
        const int k0 = t << 5;
#pragma unroll
        for (int q = 0; q < 2; ++q) {
            const int chunk = wave * 32 + q * 16;
            const __hip_bfloat16* gA = A + (size_t)(row0 + chunk + sr) * K + k0 + sk;
            __builtin_amdgcn_global_load_lds(
                (const __attribute__((address_space(1))) void*)gA,
                (__attribute__((address_space(3))) void*)&smA[buf * 4096 + chunk * 32],
                16, 0, 0);
            const __hip_bfloat16* gB = BT + (size_t)(col0 + chunk + sr) * K + k0 + sk;
            __builtin_amdgcn_global_load_lds(
                (const __attribute__((address_space(1))) void*)gB,
                (__attribute__((address_space(3))) void*)&smB[buf * 4096 + chunk * 32],
                16, 0, 0);
        }
    };

    const int nk = K >> 5;
    stage(0, 0);
    stage(1, 1);
    asm volatile("s_waitcnt vmcnt(4)" ::: "memory");   // tile 0 resident, tile 1 flying
    __builtin_amdgcn_s_barrier();

    int cur = 0;
    for (int t = 0; t < nk; ++t) {
        if (t + 2 < nk) {
            int st = cur + 2; if (st >= 3) st -= 3;
            stage(st, t + 2);                          // issue BEFORE compute
        }

        const __hip_bfloat16* sA = &smA[cur * 4096];
        const __hip_bfloat16* sB = &smB[cur * 4096];
        bf16x8 af[4], bfr[4];
#pragma unroll
        for (int i = 0; i < 4; ++i)
            af[i] = *(const bf16x8*)&sA[(wm + i * 16 + l15) * 32 + rq];
#pragma unroll
        for (int j = 0; j < 4; ++j)
            bfr[j] = *(const bf16x8*)&sB[(wn + j * 16 + l15) * 32 + rq];
#pragma unroll
        for (int i = 0; i < 4; ++i)
#pragma unroll
            for (int j = 0; j < 4; ++j)
                acc[i][j] = __builtin_amdgcn_mfma_f32_16x16x32_bf16(
                    af[i], bfr[j], acc[i][j], 0, 0, 0);

        if (t + 1 < nk) {
            if (t + 2 < nk)
                asm volatile("s_waitcnt vmcnt(4)" ::: "memory");  // t+1 done, t+2 flying
            else
                asm volatile("s_waitcnt vmcnt(0)" ::: "memory");  // tail drain
            __builtin_amdgcn_s_barrier();
        }
        cur += 1; if (cur == 3) cur = 0;
    }

    // Epilogue: D row = quad*4 + r, col = l15 (m89/m91-verified layout)
#pragma unroll
    for (int i = 0; i < 4; ++i) {
        const int mbase = row0 + wm + i * 16 + quad * 4;
#pragma unroll
        for (int j = 0; j < 4; ++j) {
            const int col = col0 + wn + j * 16 + l15;
            const float dv = SKIP ? Dvec[col] : 0.0f;
#pragma unroll
            for (int r = 0; r < 4; ++r) {
                const size_t m = (size_t)(mbase + r);
                float v = acc[i][j][r];
                if (SKIP) v += dv * __bfloat162float(Xskip[m * N + col]);
                if constexpr (sizeof(OT) == 2) {
                    C[m * N + col] = OT(v);
                } else {
                    C[m * N + col] = v;
                }
            }
        }
    }
}

// ---------------------------------------------------------------------------
// Scan pass A (vectorized): 512 blocks x 256 threads.  Block handles batch
// b = bid/64 and chunk pair 2*(bid%64)+(tid>>7); thread owns 2 adjacent p's
// (8 B loads, G13).  Local scan from zero over CHUNK=32 steps; emit S.
// ---------------------------------------------------------------------------
__global__ __launch_bounds__(256) void scan_chunks(
    const uint2* __restrict__ Bu4,     // Bu rows as 128 x uint2 (2 half2)
    const float* __restrict__ a_re, const float* __restrict__ a_im,
    float2* __restrict__ S) {
    const int bid = blockIdx.x;        // 0..511
    const int tid = threadIdx.x;
    const int b = bid >> 6;            // 0..7
    const int chunk = ((bid & 63) << 1) | (tid >> 7);  // 0..127
    const int t = tid & 127;
    const int p0 = t * 2;
    const size_t m0 = (size_t)b * LSEQ + (size_t)chunk * CHUNK;

    const float a0r = a_re[p0],     a0i = a_im[p0];
    const float a1r = a_re[p0 + 1], a1i = a_im[p0 + 1];

    float s0r = 0, s0i = 0, s1r = 0, s1i = 0;
#pragma unroll
    for (int j = 0; j < CHUNK; ++j) {
        uint2 v = Bu4[(m0 + j) * 128 + t];
        union { unsigned w; __half2 h; } c0, c1;
        c0.w = v.x; c1.w = v.y;
        float2 u0 = __half22float2(c0.h);
        float2 u1 = __half22float2(c1.h);
        float n0r = a0r * s0r - a0i * s0i + u0.x;
        float n0i = a0r * s0i + a0i * s0r + u0.y;
        float n1r = a1r * s1r - a1i * s1i + u1.x;
        float n1i = a1r * s1i + a1i * s1r + u1.y;
        s0r = n0r; s0i = n0i; s1r = n1r; s1i = n1i;
    }
    ((float4*)S)[(size_t)(b * NCHUNK + chunk) * 128 + t] =
        make_float4(s0r, s0i, s1r, s1i);
}

// ---------------------------------------------------------------------------
// Scan pass B+C fused (no grid sync needed): same block/thread mapping.
// Each thread recomputes its EXCLUSIVE carry serially from S (<=127
// dependent cFMAs; S = 2 MB -> L2-resident, ~free), then runs the local
// scan seeded with it and writes xsb (8 B stores).  Replaces the separate
// scan_carry kernel + carry buffer + one launch gap.
// ---------------------------------------------------------------------------
__global__ __launch_bounds__(256) void scan_apply(
    const uint2* __restrict__ Bu4,
    const float* __restrict__ a_re, const float* __restrict__ a_im,
    const float* __restrict__ al_re, const float* __restrict__ al_im,
    const float2* __restrict__ S,
    ushort4* __restrict__ xsb4) {
    const int bid = blockIdx.x;        // 0..511
    const int tid = threadIdx.x;
    const int b = bid >> 6;            // 0..7
    const int chunk = ((bid & 63) << 1) | (tid >> 7);  // 0..127
    const int t = tid & 127;
    const int p0 = t * 2;
    const size_t m0 = (size_t)b * LSEQ + (size_t)chunk * CHUNK;

    const float a0r = a_re[p0],      a0i = a_im[p0];
    const float a1r = a_re[p0 + 1],  a1i = a_im[p0 + 1];
    const float l0r = al_re[p0],     l0i = al_im[p0];
    const float l1r = al_re[p0 + 1], l1i = al_im[p0 + 1];

    // Exclusive carry over chunks < chunk: carry = al*carry + S[c]
    const float4* S4 = (const float4*)S;
    float s0r = 0, s0i = 0, s1r = 0, s1i = 0;
    for (int c = 0; c < chunk; ++c) {
        float4 s = S4[(size_t)(b * NCHUNK + c) * 128 + t];
        float n0r = l0r * s0r - l0i * s0i + s.x;
        float n0i = l0r * s0i + l0i * s0r + s.y;
        float n1r = l1r * s1r - l1i * s1i + s.z;
        float n1i = l1r * s1i + l1i * s1r + s.w;
        s0r = n0r; s0i = n0i; s1r = n1r; s1i = n1i;
    }

    // Local scan seeded with carry; write xs as bf16 (interleaved re/im)
#pragma unroll
    for (int j = 0; j < CHUNK; ++j) {
        uint2 v = Bu4[(m0 + j) * 128 + t];
        union { unsigned w; __half2 h; } c0, c1;
        c0.w = v.x; c1.w = v.y;
        float2 u0 = __half22float2(c0.h);
        float2 u1 = __half22float2(c1.h);
        float n0r = a0r * s0r - a0i * s0i + u0.x;
        float n0i = a0r * s0i + a0i * s0r + u0.y;
        float n1r = a1r * s1r - a1i * s1i + u1.x;
        float n1i = a1r * s1i + a1i * s1r + u1.y;
        s0r = n0r; s0i = n0i; s1r = n1r; s1i = n1i;
        union { ushort4 w4; __hip_bfloat16 h[4]; } o;
        o.h[0] = __float2bfloat16(s0r);
        o.h[1] = __float2bfloat16(s0i);
        o.h[2] = __float2bfloat16(s1r);
        o.h[3] = __float2bfloat16(s1i);
        xsb4[(m0 + j) * 128 + t] = o.w4;
    }
}

// ---------------------------------------------------------------------------
extern "C" void kernel_launch(void* const* d_in, const int* in_sizes, int n_in,
                              void* d_out, int out_size, void* d_ws, size_t ws_size,
                              hipStream_t stream) {
    const float* x       = (const float*)d_in[0];
    const float* Lre     = (const float*)d_in[1];
    const float* Lim     = (const float*)d_in[2];
    const float* Bmat    = (const float*)d_in[3];
    const float* Cmat    = (const float*)d_in[4];
    const float* Dvec    = (const float*)d_in[5];
    const float* logstep = (const float*)d_in[6];
    float* out = (float*)d_out;

    char* ws = (char*)d_ws;
    const size_t MB = 1u << 20;
    __hip_bfloat16* xb  = (__hip_bfloat16*)(ws + 0);         // 32 MB
    __hip_bfloat16* xsb = (__hip_bfloat16*)(ws + 32 * MB);   // 32 MB
    __half* Bu          = (__half*)(ws + 64 * MB);           // 32 MB
    __hip_bfloat16* W1T = (__hip_bfloat16*)(ws + 96 * MB);   // 0.5 MB
    __hip_bfloat16* W2T = (__hip_bfloat16*)(ws + 96 * MB + 512 * 1024);
    float*  a_re  = (float*)(ws + 97 * MB);
    float*  a_im  = (float*)(ws + 97 * MB + 4096);
    float*  f_re  = (float*)(ws + 97 * MB + 8192);
    float*  f_im  = (float*)(ws + 97 * MB + 12288);
    float*  al_re = (float*)(ws + 97 * MB + 16384);
    float*  al_im = (float*)(ws + 97 * MB + 20480);
    float2* S     = (float2*)(ws + 98 * MB);                 // 2 MB

    // 1. Params (1 block), then merged prep (convert + W1 + W2)
    precompute_params<<<1, 256, 0, stream>>>(Lre, Lim, logstep,
                                             f_re, f_im, a_re, a_im, al_re, al_im);
    prep<<<NCONV + 1024, 256, 0, stream>>>(x, xb, f_re, f_im, Bmat, W1T, Cmat, W2T);

    // 2. GEMM1: Bu(fp16) = xb @ W1T^T
    dim3 ggrid(MROWS / 128, NDIM / 128);  // (256, 4) = 1024 blocks, row-fast
    gemm_bt<__half, false><<<ggrid, 256, 0, stream>>>(
        xb, W1T, Bu, nullptr, nullptr, MROWS, NDIM, HDIM);

    // 3. Scan (2-pass: chunk states, then carry-inline apply), emits bf16 xs
    scan_chunks<<<512, 256, 0, stream>>>((const uint2*)Bu, a_re, a_im, S);
    scan_apply<<<512, 256, 0, stream>>>((const uint2*)Bu, a_re, a_im,
                                        al_re, al_im, S, (ushort4*)xsb);

    // 4. GEMM2: out = xsb @ W2T^T + D*xb
    dim3 ggrid2(MROWS / 128, HDIM / 128);
    gemm_bt<float, true><<<ggrid2, 256, 0, stream>>>(
        xsb, W2T, out, Dvec, xb, MROWS, HDIM, NDIM);
}

// Round 8
// 215.671 us; speedup vs baseline: 1.4590x; 1.1232x over previous
//
#include <hip/hip_runtime.h>
#include <hip/hip_bf16.h>
#include <hip/hip_fp16.h>
#include <math.h>

// Problem constants
#define BSZ 8
#define LSEQ 4096
#define HDIM 512
#define PDIM 256
#define MROWS (BSZ * LSEQ)        // 32768
#define NDIM 512                  // 2*PDIM
#define CHUNK 32
#define NCHUNK (LSEQ / CHUNK)     // 128
#define LOG2CHUNK 5

typedef __attribute__((ext_vector_type(8))) short bf16x8;
typedef __attribute__((ext_vector_type(4))) float f32x4;

// ---------------------------------------------------------------------------
// Per-p parameter kernel (256 threads, 1 block). Double-precision
// transcendentals ONCE per p. Emits f (B_bar factor), a=Lambda_bar,
// al=Lambda_bar^CHUNK.
// ---------------------------------------------------------------------------
__global__ void precompute_params(const float* __restrict__ Lre,
                                  const float* __restrict__ Lim,
                                  const float* __restrict__ logstep,
                                  float* __restrict__ f_re, float* __restrict__ f_im,
                                  float* __restrict__ a_re, float* __restrict__ a_im,
                                  float* __restrict__ al_re, float* __restrict__ al_im) {
    int p = threadIdx.x;
    if (p >= PDIM) return;
    double step = exp((double)logstep[p]);
    double dlr = (double)Lre[p], dli = (double)Lim[p];
    double mag = exp(dlr * step);
    double ar = mag * cos(dli * step);
    double ai = mag * sin(dli * step);
    double den = dlr * dlr + dli * dli;
    double nr = ar - 1.0, ni = ai;
    f_re[p] = (float)((nr * dlr + ni * dli) / den);
    f_im[p] = (float)((ni * dlr - nr * dli) / den);
    a_re[p] = (float)ar;
    a_im[p] = (float)ai;
    double cr = ar, ci = ai;
#pragma unroll
    for (int i = 0; i < LOG2CHUNK; ++i) {  // ^CHUNK
        double tr = cr * cr - ci * ci;
        double ti = 2.0 * cr * ci;
        cr = tr; ci = ti;
    }
    al_re[p] = (float)cr;
    al_im[p] = (float)ci;
}

// ---------------------------------------------------------------------------
// Weight prep only (convert_x is GONE — GEMMs consume x fp32 directly).
// 1024 blocks: [0,512) -> W1T, [512,1024) -> W2T.
// ---------------------------------------------------------------------------
__global__ __launch_bounds__(256) void prep_w(
    const float* __restrict__ f_re, const float* __restrict__ f_im,
    const float* __restrict__ Bmat, __hip_bfloat16* __restrict__ W1T,
    const float* __restrict__ Cmat, __hip_bfloat16* __restrict__ W2T) {
    const int bid = blockIdx.x;
    const int tid = threadIdx.x;
    if (bid < 512) {
        int idx = bid * 256 + tid;   // p*H + h
        int p = idx / HDIM, h = idx % HDIM;
        float fr = f_re[p], fi = f_im[p];
        float br = Bmat[(size_t)(p * HDIM + h) * 2 + 0];
        float bi = Bmat[(size_t)(p * HDIM + h) * 2 + 1];
        W1T[(size_t)(2 * p) * HDIM + h]     = __float2bfloat16(fr * br - fi * bi);
        W1T[(size_t)(2 * p + 1) * HDIM + h] = __float2bfloat16(fr * bi + fi * br);
    } else {
        int idx = (bid - 512) * 256 + tid;  // h*P + p
        int h = idx / PDIM, p = idx % PDIM;
        float cr = Cmat[(size_t)(h * PDIM + p) * 2 + 0];
        float ci = Cmat[(size_t)(h * PDIM + p) * 2 + 1];
        W2T[(size_t)h * NDIM + 2 * p]     = __float2bfloat16(2.0f * cr);
        W2T[(size_t)h * NDIM + 2 * p + 1] = __float2bfloat16(-2.0f * ci);
    }
}

// ---------------------------------------------------------------------------
// GEMM1: Bu(fp16) = x(fp32) @ W1T^T.  Same 128x128 tile / 4-wave / swizzled
// LDS layout as the proven gemm_bt, but A is REG-STAGED from fp32 with
// inline bf16 conversion (kills the separate 96 MB convert pass):
//   load 2x float4 -> cvt -> ds_write_b128 into the identical swizzled slot.
// 2-buffer __syncthreads pipeline (R2-proven; all pipeline flavors measured
// equal 43-46 us, so take the most robust one here).
// ---------------------------------------------------------------------------
__global__ __launch_bounds__(256) void gemm_xw(
    const float* __restrict__ A,            // M x K fp32 (= x)
    const __hip_bfloat16* __restrict__ BT,  // N x K bf16 (= W1T)
    __half* __restrict__ C,                 // M x N fp16 (= Bu)
    int M, int N, int K) {
    __shared__ __hip_bfloat16 smA[2 * 128 * 32];   // 16 KB
    __shared__ __hip_bfloat16 smB[2 * 128 * 32];   // 16 KB

    const int tid = threadIdx.x;
    const int lane = tid & 63;
    const int wave = tid >> 6;            // 0..3
    const int row0 = blockIdx.x * 128;    // row tile fast dim
    const int col0 = blockIdx.y * 128;
    const int wm = (wave >> 1) * 64;
    const int wn = (wave & 1) * 64;

    const int sr = lane >> 2;             // staged row within 16-row chunk
    const int swz_st = ((lane >> 2) & 3) ^ ((lane >> 4) & 3);
    const int sk = (((lane & 3) ^ swz_st) * 8);   // swizzled source k-seg (elems)
    const int quad = lane >> 4;
    const int l15 = lane & 15;
    const int rq = ((quad ^ ((l15 & 3) ^ ((l15 >> 2) & 3))) * 8);

    f32x4 acc[4][4] = {};

    auto stageB = [&](int buf, int t) {
        const int k0 = t << 5;
#pragma unroll
        for (int q = 0; q < 2; ++q) {
            const int chunk = wave * 32 + q * 16;
            const __hip_bfloat16* gB = BT + (size_t)(col0 + chunk + sr) * K + k0 + sk;
            __builtin_amdgcn_global_load_lds(
                (const __attribute__((address_space(1))) void*)gB,
                (__attribute__((address_space(3))) void*)&smB[buf * 4096 + chunk * 32],
                16, 0, 0);
        }
    };
    auto loadA = [&](int t, float4* ar) {
        const int k0 = t << 5;
#pragma unroll
        for (int q = 0; q < 2; ++q) {
            const float* gA = A + (size_t)(row0 + wave * 32 + q * 16 + sr) * K + k0 + sk;
            ar[q * 2]     = *(const float4*)gA;
            ar[q * 2 + 1] = *(const float4*)(gA + 4);
        }
    };
    auto writeA = [&](int buf, const float4* ar) {
#pragma unroll
        for (int q = 0; q < 2; ++q) {
            union { bf16x8 v; __hip_bfloat16 h[8]; } o;
            o.h[0] = __float2bfloat16(ar[q * 2].x);
            o.h[1] = __float2bfloat16(ar[q * 2].y);
            o.h[2] = __float2bfloat16(ar[q * 2].z);
            o.h[3] = __float2bfloat16(ar[q * 2].w);
            o.h[4] = __float2bfloat16(ar[q * 2 + 1].x);
            o.h[5] = __float2bfloat16(ar[q * 2 + 1].y);
            o.h[6] = __float2bfloat16(ar[q * 2 + 1].z);
            o.h[7] = __float2bfloat16(ar[q * 2 + 1].w);
            // linear dest slot (lane&3), source was XOR'd -> layout identical
            // to the gload_lds+swizzled-source scheme; read side unchanged.
            *(bf16x8*)&smA[buf * 4096 + (wave * 32 + q * 16 + sr) * 32 + (lane & 3) * 8] = o.v;
        }
    };

    const int nk = K >> 5;
    float4 ar[4];
    loadA(0, ar);
    stageB(0, 0);
    writeA(0, ar);
    __syncthreads();

    int buf = 0;
    for (int t = 0; t < nk; ++t) {
        if (t + 1 < nk) {
            loadA(t + 1, ar);            // overlap with compute below
            stageB(buf ^ 1, t + 1);
        }

        const __hip_bfloat16* sA = &smA[buf * 4096];
        const __hip_bfloat16* sB = &smB[buf * 4096];
        bf16x8 af[4], bfr[4];
#pragma unroll
        for (int i = 0; i < 4; ++i)
            af[i] = *(const bf16x8*)&sA[(wm + i * 16 + l15) * 32 + rq];
#pragma unroll
        for (int j = 0; j < 4; ++j)
            bfr[j] = *(const bf16x8*)&sB[(wn + j * 16 + l15) * 32 + rq];
#pragma unroll
        for (int i = 0; i < 4; ++i)
#pragma unroll
            for (int j = 0; j < 4; ++j)
                acc[i][j] = __builtin_amdgcn_mfma_f32_16x16x32_bf16(
                    af[i], bfr[j], acc[i][j], 0, 0, 0);

        if (t + 1 < nk) writeA(buf ^ 1, ar);
        __syncthreads();
        buf ^= 1;
    }

    // Epilogue: D row = quad*4 + r, col = l15 (m89/m91-verified layout)
#pragma unroll
    for (int i = 0; i < 4; ++i) {
        const int mbase = row0 + wm + i * 16 + quad * 4;
#pragma unroll
        for (int j = 0; j < 4; ++j) {
            const int col = col0 + wn + j * 16 + l15;
#pragma unroll
            for (int r = 0; r < 4; ++r) {
                const size_t m = (size_t)(mbase + r);
                C[m * N + col] = __half(acc[i][j][r]);
            }
        }
    }
}

// ---------------------------------------------------------------------------
// GEMM2 (R4-proven, verbatim except skip reads x fp32): out = xsb @ W2T^T
// + D*x.  128x128 tile, 3-buffer counted-vmcnt pipeline, T2 swizzle.
// ---------------------------------------------------------------------------
__global__ __launch_bounds__(256) void gemm_bt_skip(
    const __hip_bfloat16* __restrict__ A,   // M x K (xsb)
    const __hip_bfloat16* __restrict__ BT,  // N x K (W2T)
    float* __restrict__ C,                  // M x N
    const float* __restrict__ Dvec,
    const float* __restrict__ Xskip,        // M x N fp32 (= x)
    int M, int N, int K) {
    __shared__ __hip_bfloat16 smA[3 * 128 * 32];   // 24 KB
    __shared__ __hip_bfloat16 smB[3 * 128 * 32];   // 24 KB

    const int tid = threadIdx.x;
    const int lane = tid & 63;
    const int wave = tid >> 6;            // 0..3
    const int row0 = blockIdx.x * 128;    // row tile fast dim
    const int col0 = blockIdx.y * 128;
    const int wm = (wave >> 1) * 64;
    const int wn = (wave & 1) * 64;

    const int sr = lane >> 2;
    const int swz_st = ((lane >> 2) & 3) ^ ((lane >> 4) & 3);
    const int sk = (((lane & 3) ^ swz_st) * 8);
    const int quad = lane >> 4;
    const int l15 = lane & 15;
    const int rq = ((quad ^ ((l15 & 3) ^ ((l15 >> 2) & 3))) * 8);

    f32x4 acc[4][4] = {};

    auto stage = [&](int buf, int t) {
        const int k0 = t << 5;
#pragma unroll
        for (int q = 0; q < 2; ++q) {
            const int chunk = wave * 32 + q * 16;
            const __hip_bfloat16* gA = A + (size_t)(row0 + chunk + sr) * K + k0 + sk;
            __builtin_amdgcn_global_load_lds(
                (const __attribute__((address_space(1))) void*)gA,
                (__attribute__((address_space(3))) void*)&smA[buf * 4096 + chunk * 32],
                16, 0, 0);
            const __hip_bfloat16* gB = BT + (size_t)(col0 + chunk + sr) * K + k0 + sk;
            __builtin_amdgcn_global_load_lds(
                (const __attribute__((address_space(1))) void*)gB,
                (__attribute__((address_space(3))) void*)&smB[buf * 4096 + chunk * 32],
                16, 0, 0);
        }
    };

    const int nk = K >> 5;
    stage(0, 0);
    stage(1, 1);
    asm volatile("s_waitcnt vmcnt(4)" ::: "memory");
    __builtin_amdgcn_s_barrier();

    int cur = 0;
    for (int t = 0; t < nk; ++t) {
        if (t + 2 < nk) {
            int st = cur + 2; if (st >= 3) st -= 3;
            stage(st, t + 2);
        }

        const __hip_bfloat16* sA = &smA[cur * 4096];
        const __hip_bfloat16* sB = &smB[cur * 4096];
        bf16x8 af[4], bfr[4];
#pragma unroll
        for (int i = 0; i < 4; ++i)
            af[i] = *(const bf16x8*)&sA[(wm + i * 16 + l15) * 32 + rq];
#pragma unroll
        for (int j = 0; j < 4; ++j)
            bfr[j] = *(const bf16x8*)&sB[(wn + j * 16 + l15) * 32 + rq];
#pragma unroll
        for (int i = 0; i < 4; ++i)
#pragma unroll
            for (int j = 0; j < 4; ++j)
                acc[i][j] = __builtin_amdgcn_mfma_f32_16x16x32_bf16(
                    af[i], bfr[j], acc[i][j], 0, 0, 0);

        if (t + 1 < nk) {
            if (t + 2 < nk)
                asm volatile("s_waitcnt vmcnt(4)" ::: "memory");
            else
                asm volatile("s_waitcnt vmcnt(0)" ::: "memory");
            __builtin_amdgcn_s_barrier();
        }
        cur += 1; if (cur == 3) cur = 0;
    }

#pragma unroll
    for (int i = 0; i < 4; ++i) {
        const int mbase = row0 + wm + i * 16 + quad * 4;
#pragma unroll
        for (int j = 0; j < 4; ++j) {
            const int col = col0 + wn + j * 16 + l15;
            const float dv = Dvec[col];
#pragma unroll
            for (int r = 0; r < 4; ++r) {
                const size_t m = (size_t)(mbase + r);
                C[m * N + col] = acc[i][j][r] + dv * Xskip[m * N + col];
            }
        }
    }
}

// ---------------------------------------------------------------------------
// Scan trio (R4-exact, CHUNK=32): pass A 1024 blocks, pass B 512 blocks
// wave-parallel shuffle scan, pass C 1024 blocks.
// ---------------------------------------------------------------------------
__global__ __launch_bounds__(256) void scan_chunks(const __half2* __restrict__ Bu2,
                                                   const float* __restrict__ a_re,
                                                   const float* __restrict__ a_im,
                                                   float2* __restrict__ S) {
    int b = blockIdx.x / NCHUNK;
    int c = blockIdx.x % NCHUNK;
    int p = threadIdx.x;
    float ar = a_re[p], ai = a_im[p];
    float sr = 0.0f, si = 0.0f;
    size_t m0 = (size_t)b * LSEQ + (size_t)c * CHUNK;
    for (int j = 0; j < CHUNK; ++j) {
        float2 u = __half22float2(Bu2[(m0 + j) * PDIM + p]);
        float nsr = ar * sr - ai * si + u.x;
        float nsi = ar * si + ai * sr + u.y;
        sr = nsr; si = nsi;
    }
    S[(size_t)(b * NCHUNK + c) * PDIM + p] = make_float2(sr, si);
}

__global__ __launch_bounds__(256) void scan_carry(const float2* __restrict__ S,
                                                  const float* __restrict__ al_re,
                                                  const float* __restrict__ al_im,
                                                  float2* __restrict__ carry) {
    const int wid = blockIdx.x * 4 + (threadIdx.x >> 6);  // 0..2047
    const int b = wid >> 8;        // 0..7
    const int p = wid & 255;       // 0..255
    const int lane = threadIdx.x & 63;
    const int c0 = 2 * lane, c1 = 2 * lane + 1;
    float alr = al_re[p], ali = al_im[p];
    float2 s0 = S[(size_t)(b * NCHUNK + c0) * PDIM + p];
    float2 s1 = S[(size_t)(b * NCHUNK + c1) * PDIM + p];
    float Ar = alr * alr - ali * ali;
    float Ai = 2.0f * alr * ali;
    float br = alr * s0.x - ali * s0.y + s1.x;
    float bi = alr * s0.y + ali * s0.x + s1.y;
#pragma unroll
    for (int d = 1; d < 64; d <<= 1) {
        float pAr = __shfl_up(Ar, d);
        float pAi = __shfl_up(Ai, d);
        float pbr = __shfl_up(br, d);
        float pbi = __shfl_up(bi, d);
        if (lane >= d) {
            float nAr = Ar * pAr - Ai * pAi;
            float nAi = Ar * pAi + Ai * pAr;
            float nbr = Ar * pbr - Ai * pbi + br;
            float nbi = Ar * pbi + Ai * pbr + bi;
            Ar = nAr; Ai = nAi; br = nbr; bi = nbi;
        }
    }
    float er = __shfl_up(br, 1);
    float ei = __shfl_up(bi, 1);
    if (lane == 0) { er = 0.0f; ei = 0.0f; }
    carry[(size_t)(b * NCHUNK + c0) * PDIM + p] = make_float2(er, ei);
    carry[(size_t)(b * NCHUNK + c1) * PDIM + p] =
        make_float2(alr * er - ali * ei + s0.x, alr * ei + ali * er + s0.y);
}

__global__ __launch_bounds__(256) void scan_apply(const __half2* __restrict__ Bu2,
                                                  const float* __restrict__ a_re,
                                                  const float* __restrict__ a_im,
                                                  const float2* __restrict__ carry,
                                                  ushort2* __restrict__ xsb2) {
    int b = blockIdx.x / NCHUNK;
    int c = blockIdx.x % NCHUNK;
    int p = threadIdx.x;
    float ar = a_re[p], ai = a_im[p];
    float2 c0 = carry[(size_t)(b * NCHUNK + c) * PDIM + p];
    float sr = c0.x, si = c0.y;
    size_t m0 = (size_t)b * LSEQ + (size_t)c * CHUNK;
    for (int j = 0; j < CHUNK; ++j) {
        size_t idx = (m0 + j) * PDIM + p;
        float2 u = __half22float2(Bu2[idx]);
        float nsr = ar * sr - ai * si + u.x;
        float nsi = ar * si + ai * sr + u.y;
        sr = nsr; si = nsi;
        union { ushort2 u2; __hip_bfloat16 h[2]; } o;
        o.h[0] = __float2bfloat16(sr);
        o.h[1] = __float2bfloat16(si);
        xsb2[idx] = o.u2;
    }
}

// ---------------------------------------------------------------------------
extern "C" void kernel_launch(void* const* d_in, const int* in_sizes, int n_in,
                              void* d_out, int out_size, void* d_ws, size_t ws_size,
                              hipStream_t stream) {
    const float* x       = (const float*)d_in[0];
    const float* Lre     = (const float*)d_in[1];
    const float* Lim     = (const float*)d_in[2];
    const float* Bmat    = (const float*)d_in[3];
    const float* Cmat    = (const float*)d_in[4];
    const float* Dvec    = (const float*)d_in[5];
    const float* logstep = (const float*)d_in[6];
    float* out = (float*)d_out;

    char* ws = (char*)d_ws;
    const size_t MB = 1u << 20;
    __hip_bfloat16* xsb = (__hip_bfloat16*)(ws + 0);         // 32 MB
    __half* Bu          = (__half*)(ws + 32 * MB);           // 32 MB
    __hip_bfloat16* W1T = (__hip_bfloat16*)(ws + 64 * MB);   // 0.5 MB
    __hip_bfloat16* W2T = (__hip_bfloat16*)(ws + 64 * MB + 512 * 1024);
    float*  a_re  = (float*)(ws + 65 * MB);
    float*  a_im  = (float*)(ws + 65 * MB + 4096);
    float*  f_re  = (float*)(ws + 65 * MB + 8192);
    float*  f_im  = (float*)(ws + 65 * MB + 12288);
    float*  al_re = (float*)(ws + 65 * MB + 16384);
    float*  al_im = (float*)(ws + 65 * MB + 20480);
    float2* S     = (float2*)(ws + 66 * MB);                 // 1 MB
    float2* carry = (float2*)(ws + 68 * MB);                 // 1 MB

    // 1. Params (1 block) + weight prep (1024 blocks). No x conversion.
    precompute_params<<<1, 256, 0, stream>>>(Lre, Lim, logstep,
                                             f_re, f_im, a_re, a_im, al_re, al_im);
    prep_w<<<1024, 256, 0, stream>>>(f_re, f_im, Bmat, W1T, Cmat, W2T);

    // 2. GEMM1: Bu(fp16) = x(fp32) @ W1T^T  (reg-staged A + inline cvt)
    dim3 ggrid(MROWS / 128, NDIM / 128);  // (256, 4), row-fast
    gemm_xw<<<ggrid, 256, 0, stream>>>(x, W1T, Bu, MROWS, NDIM, HDIM);

    // 3. Scan (R4-exact 3-pass), emits xs as bf16
    scan_chunks<<<BSZ * NCHUNK, 256, 0, stream>>>((const __half2*)Bu, a_re, a_im, S);
    scan_carry<<<BSZ * PDIM / 4, 256, 0, stream>>>(S, al_re, al_im, carry);
    scan_apply<<<BSZ * NCHUNK, 256, 0, stream>>>((const __half2*)Bu, a_re, a_im,
                                                 carry, (ushort2*)xsb);

    // 4. GEMM2: out = xsb @ W2T^T + D*x (skip from fp32 x directly)
    dim3 ggrid2(MROWS / 128, HDIM / 128);
    gemm_bt_skip<<<ggrid2, 256, 0, stream>>>(
        xsb, W2T, out, Dvec, x, MROWS, HDIM, NDIM);
}